// Round 5
// baseline (200.677 us; speedup 1.0000x reference)
//
#include <hip/hip_runtime.h>
#include <math.h>

#define B_   32
#define T_   1024
#define IN_  512
#define HID_ 512
#define HYP_ 256
#define M_   (B_ * T_)   // 32768

typedef _Float16 half8_t __attribute__((ext_vector_type(8)));
typedef float    f32x4   __attribute__((ext_vector_type(4)));

typedef __attribute__((address_space(1))) const void* gptr_as1;
typedef __attribute__((address_space(3))) void*       lptr_as3;

__device__ __forceinline__ void gload_lds16(const void* g, void* l) {
    // async global->LDS, 16B/lane; LDS dest = wave-uniform base + lane*16
    __builtin_amdgcn_global_load_lds((gptr_as1)g, (lptr_as3)l, 16, 0, 0);
}

// ---------------------------------------------------------------------------
// One fused fp32->fp16 conversion pass: x (8192 blocks) + Ws(64) + Wm(32) +
// We(64) + W2(128). Each thread converts 8 contiguous floats.
// ---------------------------------------------------------------------------
__global__ __launch_bounds__(256) void cvt_all(
    const float* __restrict__ x,  _Float16* __restrict__ xh,
    const float* __restrict__ Ws, _Float16* __restrict__ wsh,
    const float* __restrict__ Wm, _Float16* __restrict__ wmh,
    const float* __restrict__ We, _Float16* __restrict__ weh,
    const float* __restrict__ W2, _Float16* __restrict__ w2h)
{
    const int blk = blockIdx.x;
    const float* src; _Float16* dst; int base;
    if      (blk < 8192) { src = x;  dst = xh;  base = blk; }
    else if (blk < 8256) { src = Ws; dst = wsh; base = blk - 8192; }
    else if (blk < 8288) { src = Wm; dst = wmh; base = blk - 8256; }
    else if (blk < 8352) { src = We; dst = weh; base = blk - 8288; }
    else                 { src = W2; dst = w2h; base = blk - 8352; }
    const int i = base * 2048 + threadIdx.x * 8;
    f32x4 v0 = *(const f32x4*)(src + i);
    f32x4 v1 = *(const f32x4*)(src + i + 4);
    half8_t h;
    h[0] = (_Float16)v0[0]; h[1] = (_Float16)v0[1];
    h[2] = (_Float16)v0[2]; h[3] = (_Float16)v0[3];
    h[4] = (_Float16)v1[0]; h[5] = (_Float16)v1[1];
    h[6] = (_Float16)v1[2]; h[7] = (_Float16)v1[3];
    *(half8_t*)(dst + i) = h;
}

// ---------------------------------------------------------------------------
// Fragment-order LDS staging for a 128-row x 32-half tile (8 KiB).
// LDS slot s (16B each) = g*64 + c*16 + r, holding global (row g*16+r,
// k-chunk c). The wave's ds_read_b128 of fragment group g is lane-contiguous
// (lane*16) -> conflict-free. global_load_lds writes linearly; the
// permutation lives in the SOURCE address (rule: both-sides-or-neither).
// ---------------------------------------------------------------------------
__device__ __forceinline__ void stage_frag(const _Float16* src, int K,
                                           _Float16* lds, int tid)
{
#pragma unroll
    for (int q = 0; q < 2; ++q) {
        const int s = q * 256 + tid;
        const int g = s >> 6, c = (s >> 4) & 3, r = s & 15;
        const char* gp = (const char*)src + (size_t)(g * 16 + r) * (K * 2) + c * 16;
        char* lp = (char*)lds + (q * 256 + (tid & ~63)) * 16;   // wave-uniform
        gload_lds16(gp, lp);
    }
}

// ---------------------------------------------------------------------------
// C[M,N](f16) = relu(A(f16)[M,K] @ W(f16)[N,K]^T + bias). 128x128 tile, BK=32,
// 4 waves (2x2), 4x4 frags of mfma_f32_16x16x32_f16 per wave.
// Double-buffered LDS: stage tile kt+1 BEFORE computing tile kt, so the
// global_load_lds latency hides under ds_read+MFMA (T3 minimum 2-phase).
// ---------------------------------------------------------------------------
__global__ __launch_bounds__(256) void gemm_relu(
    const _Float16* __restrict__ A, const _Float16* __restrict__ W,
    const float* __restrict__ bias, _Float16* __restrict__ C, int N, int K)
{
    __shared__ __align__(16) _Float16 As[2][128 * 32];
    __shared__ __align__(16) _Float16 Bs[2][128 * 32];

    const int tid = threadIdx.x;
    const int m0 = blockIdx.x * 128, n0 = blockIdx.y * 128;
    const int lane = tid & 63;
    const int wr = (tid >> 7) & 1, wc = (tid >> 6) & 1;
    const int lq = lane >> 4, lr = lane & 15;

    f32x4 zero = {0.f, 0.f, 0.f, 0.f};
    f32x4 acc[4][4];
#pragma unroll
    for (int i = 0; i < 4; ++i)
#pragma unroll
        for (int j = 0; j < 4; ++j) acc[i][j] = zero;

    const int ktiles = K >> 5;
    stage_frag(A + (size_t)m0 * K, K, As[0], tid);
    stage_frag(W + (size_t)n0 * K, K, Bs[0], tid);
    __syncthreads();

    int cur = 0;
    for (int kt = 0; kt < ktiles; ++kt) {
        if (kt + 1 < ktiles) {
            stage_frag(A + (size_t)m0 * K + (kt + 1) * 32, K, As[cur ^ 1], tid);
            stage_frag(W + (size_t)n0 * K + (kt + 1) * 32, K, Bs[cur ^ 1], tid);
        }
        half8_t af[4], wf[4];
#pragma unroll
        for (int i = 0; i < 4; ++i)
            af[i] = *(const half8_t*)((const char*)As[cur] + (wr * 4 + i) * 1024 + lane * 16);
#pragma unroll
        for (int j = 0; j < 4; ++j)
            wf[j] = *(const half8_t*)((const char*)Bs[cur] + (wc * 4 + j) * 1024 + lane * 16);
#pragma unroll
        for (int i = 0; i < 4; ++i)
#pragma unroll
            for (int j = 0; j < 4; ++j)
                acc[i][j] = __builtin_amdgcn_mfma_f32_16x16x32_f16(af[i], wf[j], acc[i][j], 0, 0, 0);
        __syncthreads();   // drains this iter's stage loads too (vmcnt+barrier)
        cur ^= 1;
    }

#pragma unroll
    for (int j = 0; j < 4; ++j) {
        const int col = n0 + wc * 64 + j * 16 + lr;
        const float bv = bias[col];
#pragma unroll
        for (int i = 0; i < 4; ++i) {
            const int rbase = m0 + wr * 64 + i * 16 + lq * 4;
#pragma unroll
            for (int rg = 0; rg < 4; ++rg) {
                float v = acc[i][j][rg] + bv;
                C[(size_t)(rbase + rg) * N + col] = (_Float16)fmaxf(v, 0.f);
            }
        }
    }
}

// ---------------------------------------------------------------------------
// Fused G3+G4: Out(f32) = (h2 @ We^T + be) * sigmoid(xh @ W2^T + b2).
// One unified 24-step double-buffered pipeline (8 steps K=256 arm, 16 steps
// K=512 arm) -- no drain at the phase junction. acc1/acc2 are separate named
// arrays selected by a uniform branch (all indices static).
// ---------------------------------------------------------------------------
__global__ __launch_bounds__(256) void gemm_g34(
    const _Float16* __restrict__ h2h, const _Float16* __restrict__ weh,
    const float* __restrict__ be,
    const _Float16* __restrict__ xh, const _Float16* __restrict__ w2h,
    const float* __restrict__ b2,
    float* __restrict__ Out)
{
    __shared__ __align__(16) _Float16 As[2][128 * 32];
    __shared__ __align__(16) _Float16 Bs[2][128 * 32];

    const int tid = threadIdx.x;
    const int m0 = blockIdx.x * 128, n0 = blockIdx.y * 128;
    const int lane = tid & 63;
    const int wr = (tid >> 7) & 1, wc = (tid >> 6) & 1;
    const int lq = lane >> 4, lr = lane & 15;

    f32x4 zero = {0.f, 0.f, 0.f, 0.f};
    f32x4 acc1[4][4], acc2[4][4];
#pragma unroll
    for (int i = 0; i < 4; ++i)
#pragma unroll
        for (int j = 0; j < 4; ++j) { acc1[i][j] = zero; acc2[i][j] = zero; }

    const int NSTEP = HYP_ / 32 + IN_ / 32;   // 8 + 16 = 24

    // step s sources: s<8 -> (h2h,weh,K=256,koff=s*32); else (xh,w2h,K=512)
    stage_frag(h2h + (size_t)m0 * HYP_, HYP_, As[0], tid);
    stage_frag(weh + (size_t)n0 * HYP_, HYP_, Bs[0], tid);
    __syncthreads();

    int cur = 0;
    for (int s = 0; s < NSTEP; ++s) {
        const int sn = s + 1;
        if (sn < NSTEP) {
            if (sn < 8) {
                stage_frag(h2h + (size_t)m0 * HYP_ + sn * 32, HYP_, As[cur ^ 1], tid);
                stage_frag(weh + (size_t)n0 * HYP_ + sn * 32, HYP_, Bs[cur ^ 1], tid);
            } else {
                stage_frag(xh  + (size_t)m0 * IN_ + (sn - 8) * 32, IN_, As[cur ^ 1], tid);
                stage_frag(w2h + (size_t)n0 * IN_ + (sn - 8) * 32, IN_, Bs[cur ^ 1], tid);
            }
        }
        half8_t af[4], wf[4];
#pragma unroll
        for (int i = 0; i < 4; ++i)
            af[i] = *(const half8_t*)((const char*)As[cur] + (wr * 4 + i) * 1024 + lane * 16);
#pragma unroll
        for (int j = 0; j < 4; ++j)
            wf[j] = *(const half8_t*)((const char*)Bs[cur] + (wc * 4 + j) * 1024 + lane * 16);
        if (s < 8) {
#pragma unroll
            for (int i = 0; i < 4; ++i)
#pragma unroll
                for (int j = 0; j < 4; ++j)
                    acc1[i][j] = __builtin_amdgcn_mfma_f32_16x16x32_f16(af[i], wf[j], acc1[i][j], 0, 0, 0);
        } else {
#pragma unroll
            for (int i = 0; i < 4; ++i)
#pragma unroll
                for (int j = 0; j < 4; ++j)
                    acc2[i][j] = __builtin_amdgcn_mfma_f32_16x16x32_f16(af[i], wf[j], acc2[i][j], 0, 0, 0);
        }
        __syncthreads();
        cur ^= 1;
    }

#pragma unroll
    for (int j = 0; j < 4; ++j) {
        const int col = n0 + wc * 64 + j * 16 + lr;
        const float bev = be[col];
        const float b2v = b2[col];
#pragma unroll
        for (int i = 0; i < 4; ++i) {
            const int rbase = m0 + wr * 64 + i * 16 + lq * 4;
#pragma unroll
            for (int rg = 0; rg < 4; ++rg) {
                float fc = acc1[i][j][rg] + bev;
                float sg = acc2[i][j][rg] + b2v;
                sg = 1.f / (1.f + __expf(-sg));
                Out[(size_t)(rbase + rg) * HID_ + col] = fc * sg;
            }
        }
    }
}

// ---------------------------------------------------------------------------
// Scan: h_t[j] = relu(h_{t-1}[(j-1)&511] + b_t[j]) -> 16384 independent
// diagonal chains (chain r of batch b touches (t, (r+t)&511)). One thread per
// chain, 32-deep register prefetch (32 outstanding 256B loads/wave doubles
// the per-wave HBM BW vs 16-deep at 1 wave/CU), in-place over b.
// ---------------------------------------------------------------------------
__global__ __launch_bounds__(64) void srnn_chain(const float* __restrict__ hidden,
                                                 float* bio, float* hlast)
{
    const int g = blockIdx.x * 64 + threadIdx.x;
    const int b = g >> 9;
    const int r = g & 511;
    float* base = bio + (size_t)b * (T_ * HID_);

    float c = hidden[b * HID_ + ((r + 511) & 511)];   // h_{-1}[(r-1) mod 512]

    float buf[32];
#pragma unroll
    for (int u = 0; u < 32; ++u)
        buf[u] = base[u * 512 + ((r + u) & 511)];

    for (int tb = 0; tb < T_; tb += 32) {
#pragma unroll
        for (int u = 0; u < 32; ++u) {
            const int t = tb + u;
            c = fmaxf(c + buf[u], 0.f);
            base[t * 512 + ((r + t) & 511)] = c;
            const int tn = t + 32;
            if (tn < T_)   // uniform branch
                buf[u] = base[tn * 512 + ((r + tn) & 511)];
        }
    }
    hlast[b * HID_ + ((r + 1023) & 511)] = c;
}

extern "C" void kernel_launch(void* const* d_in, const int* in_sizes, int n_in,
                              void* d_out, int out_size, void* d_ws, size_t ws_size,
                              hipStream_t stream)
{
    const float* x      = (const float*)d_in[0];  // [B,T,IN]
    const float* hidden = (const float*)d_in[1];  // [B,HID]
    const float* Ws     = (const float*)d_in[2];  // [HYP,IN]
    const float* bs     = (const float*)d_in[3];
    const float* Wm     = (const float*)d_in[4];  // [HYP,HYP]
    const float* bm     = (const float*)d_in[5];
    const float* We     = (const float*)d_in[6];  // [HID,HYP]
    const float* be     = (const float*)d_in[7];
    const float* W2     = (const float*)d_in[8];  // [HID,IN]
    const float* b2     = (const float*)d_in[9];

    float* outputs = (float*)d_out;                 // [B,T,HID]
    float* hlast   = outputs + (size_t)M_ * HID_;   // [B,HID]

    // workspace: xh 32MB | h2h 16MB | 4 fp16 weights ~1.2MB  (~49MB total)
    _Float16* xh  = (_Float16*)d_ws;                // [M,IN]
    _Float16* h2h = xh + (size_t)M_ * IN_;          // [M,HYP]
    _Float16* wsh = h2h + (size_t)M_ * HYP_;        // [HYP,IN]
    _Float16* wmh = wsh + HYP_ * IN_;               // [HYP,HYP]
    _Float16* weh = wmh + HYP_ * HYP_;              // [HID,HYP]
    _Float16* w2h = weh + HID_ * HYP_;              // [HID,IN]

    // h1 (16MB fp16) staged in the front of d_out; dead before gemm_g34
    // overwrites the region (kernels are stream-ordered).
    _Float16* h1h = (_Float16*)d_out;

    // fp32 -> fp16: x and all weights, one pass
    cvt_all<<<dim3(8480), 256, 0, stream>>>(x, xh, Ws, wsh, Wm, wmh, We, weh, W2, w2h);
    // h1 = relu(xh @ Ws^T + bs)
    gemm_relu<<<dim3(M_ / 128, HYP_ / 128), 256, 0, stream>>>(xh, wsh, bs, h1h, HYP_, IN_);
    // h2 = relu(h1 @ Wm^T + bm)
    gemm_relu<<<dim3(M_ / 128, HYP_ / 128), 256, 0, stream>>>(h1h, wmh, bm, h2h, HYP_, HYP_);
    // outputs = (h2 @ We^T + be) * sigmoid(xh @ W2^T + b2)
    gemm_g34<<<dim3(M_ / 128, HID_ / 128), 256, 0, stream>>>(h2h, weh, be, xh, w2h, b2, outputs);
    // scan (in place) + hlast
    srnn_chain<<<dim3((B_ * HID_) / 64), dim3(64), 0, stream>>>(hidden, outputs, hlast);
}

// Round 6
// 178.151 us; speedup vs baseline: 1.1264x; 1.1264x over previous
//
#include <hip/hip_runtime.h>
#include <math.h>

#define B_   32
#define T_   1024
#define IN_  512
#define HID_ 512
#define HYP_ 256
#define M_   (B_ * T_)   // 32768
#define R_   64          // rows per fused block

// LDS map (bytes): xs 64K | h1s 32K | h2s 32K | stg 16K  = 144 KiB
#define XS_OFF   0
#define H1S_OFF  65536
#define H2S_OFF  98304
#define STG_OFF  131072
#define LDS_BYTES 147456

typedef _Float16 half8_t __attribute__((ext_vector_type(8)));
typedef _Float16 half4_t __attribute__((ext_vector_type(4)));
typedef float    f32x4   __attribute__((ext_vector_type(4)));

typedef __attribute__((address_space(1))) const void* gptr_as1;
typedef __attribute__((address_space(3))) void*       lptr_as3;

__device__ __forceinline__ void gload_lds16(const void* g, void* l) {
    // async global->LDS, 16B/lane; LDS dest = wave-uniform base + lane*16
    __builtin_amdgcn_global_load_lds((gptr_as1)g, (lptr_as3)l, 16, 0, 0);
}

// ---------------------------------------------------------------------------
// fp32 -> fp16 weights only (1.3 MB out). 2048 elems/block.
// sizes: Ws 131072 | Wm 65536 | We 131072 | W2 262144  -> 64|32|64|128 blocks
// ---------------------------------------------------------------------------
__global__ __launch_bounds__(256) void cvt_w(
    const float* __restrict__ Ws, _Float16* __restrict__ wsh,
    const float* __restrict__ Wm, _Float16* __restrict__ wmh,
    const float* __restrict__ We, _Float16* __restrict__ weh,
    const float* __restrict__ W2, _Float16* __restrict__ w2h)
{
    const int blk = blockIdx.x;
    const float* src; _Float16* dst; int base;
    if      (blk < 64)  { src = Ws; dst = wsh; base = blk; }
    else if (blk < 96)  { src = Wm; dst = wmh; base = blk - 64; }
    else if (blk < 160) { src = We; dst = weh; base = blk - 96; }
    else                { src = W2; dst = w2h; base = blk - 160; }
    const int i = base * 2048 + threadIdx.x * 8;
    f32x4 v0 = *(const f32x4*)(src + i);
    f32x4 v1 = *(const f32x4*)(src + i + 4);
    half8_t h;
    h[0] = (_Float16)v0[0]; h[1] = (_Float16)v0[1];
    h[2] = (_Float16)v0[2]; h[3] = (_Float16)v0[3];
    h[4] = (_Float16)v1[0]; h[5] = (_Float16)v1[1];
    h[6] = (_Float16)v1[2]; h[7] = (_Float16)v1[3];
    *(half8_t*)(dst + i) = h;
}

// ---------------------------------------------------------------------------
// Fragment-order staging of a 256-row x 32-half weight tile (16 KiB) with
// 512 threads. LDS slot s (16B) = g*64 + c2*16 + r holds rows g*16+r,
// halfs [c2*8, c2*8+8) of the 32-chunk. Source address carries the
// permutation; LDS dest is linear (both-sides-or-neither rule).
// ---------------------------------------------------------------------------
__device__ __forceinline__ void stage512(const _Float16* src, int K,
                                         char* ldsbase, int tid)
{
#pragma unroll
    for (int q = 0; q < 2; ++q) {
        const int s = q * 512 + tid;
        const int g = s >> 6, c2 = (s >> 4) & 3, r = s & 15;
        const char* gp = (const char*)src + (size_t)(g * 16 + r) * (K * 2) + c2 * 16;
        char* lp = ldsbase + (q * 512 + (tid & ~63)) * 16;   // wave-uniform
        gload_lds16(gp, lp);
    }
}

// one k-step: A frag-group pair (wm) x B frag-quad (wn), 8 MFMAs
__device__ __forceinline__ void do_step(const char* ab, const char* bb,
                                        int wm, int wn, int lane,
                                        f32x4 acc[2][4])
{
    half8_t af0 = *(const half8_t*)(ab + (wm * 2 + 0) * 1024 + lane * 16);
    half8_t af1 = *(const half8_t*)(ab + (wm * 2 + 1) * 1024 + lane * 16);
#pragma unroll
    for (int j = 0; j < 4; ++j) {
        half8_t wf = *(const half8_t*)(bb + (wn * 4 + j) * 1024 + lane * 16);
        acc[0][j] = __builtin_amdgcn_mfma_f32_16x16x32_f16(af0, wf, acc[0][j], 0, 0, 0);
        acc[1][j] = __builtin_amdgcn_mfma_f32_16x16x32_f16(af1, wf, acc[1][j], 0, 0, 0);
    }
}

// bias+relu epilogue, scatter fp16 into fragment-order LDS (A for next phase)
__device__ __forceinline__ void epi_relu_lds(char* dst, const f32x4 acc[2][4],
                                             const float* __restrict__ bias,
                                             int wm, int wn, int lq, int lr)
{
#pragma unroll
    for (int j = 0; j < 4; ++j) {
        const int col = wn * 64 + j * 16 + lr;
        const float bv = bias[col];
        const int cpart = (col >> 5) * 4096 + ((col & 31) >> 3) * 256 + (col & 7) * 2;
#pragma unroll
        for (int i = 0; i < 2; ++i) {
#pragma unroll
            for (int rg = 0; rg < 4; ++rg) {
                const int row = wm * 32 + i * 16 + lq * 4 + rg;
                const float v = fmaxf(acc[i][j][rg] + bv, 0.f);
                *(_Float16*)(dst + cpart + (row >> 4) * 1024 + (row & 15) * 16) =
                    (_Float16)v;
            }
        }
    }
}

// ---------------------------------------------------------------------------
// Fused MLP: per 64-row m-tile, x is converted into LDS once; h1,h2 live in
// LDS; only weight tiles are staged per k-step (dbuf into dead LDS regions).
//   h1 = relu(x@Ws^T+bs)  [K=512, 16 steps]   stage dbuf: STG / H2S(dead)
//   h2 = relu(h1@Wm^T+bm) [K=256,  8 steps]   stage dbuf: STG / H2S(dead)
//   out = (h2@We^T+be) * sigmoid(x@W2^T+b2)   per 256-col half: 8+16 steps,
//                                             stage dbuf: STG / H1S(dead)
// 8 waves = 2(m) x 4(n); per wave 2x4 fp32x4 accs per arm.
// ---------------------------------------------------------------------------
__global__ __launch_bounds__(512, 2) void fused_mlp(
    const float* __restrict__ x,
    const _Float16* __restrict__ wsh, const float* __restrict__ bs,
    const _Float16* __restrict__ wmh, const float* __restrict__ bm,
    const _Float16* __restrict__ weh, const float* __restrict__ be,
    const _Float16* __restrict__ w2h, const float* __restrict__ b2,
    float* __restrict__ Out)
{
    __shared__ __align__(16) char lds[LDS_BYTES];

    const int tid  = threadIdx.x;
    const int m0   = blockIdx.x * R_;
    const int lane = tid & 63;
    const int wave = tid >> 6;
    const int wm = wave >> 2;        // 0..1  (m)
    const int wn = wave & 3;         // 0..3  (n)
    const int lq = lane >> 4, lr = lane & 15;

    // ---- x tile: fp32 HBM -> fp16 fragment-order LDS (once) ----
#pragma unroll
    for (int v = 0; v < 16; ++v) {
        const int idx = v * 2048 + tid * 4;      // 0..32767
        const int row = idx >> 9, k = idx & 511; // k % 4 == 0
        f32x4 xv = *(const f32x4*)(x + (size_t)(m0 + row) * IN_ + k);
        half4_t h;
        h[0] = (_Float16)xv[0]; h[1] = (_Float16)xv[1];
        h[2] = (_Float16)xv[2]; h[3] = (_Float16)xv[3];
        const int byteoff = XS_OFF + (k >> 5) * 4096 + (row >> 4) * 1024 +
                            ((k & 31) >> 3) * 256 + (row & 15) * 16 + (k & 7) * 2;
        *(half4_t*)(lds + byteoff) = h;
    }
    __syncthreads();

    const f32x4 zero = {0.f, 0.f, 0.f, 0.f};

    // ---- phase 1: h1 = relu(x @ Ws^T + bs), K=512 ----
    {
        f32x4 acc[2][4];
#pragma unroll
        for (int i = 0; i < 2; ++i)
#pragma unroll
            for (int j = 0; j < 4; ++j) acc[i][j] = zero;

        stage512(wsh, IN_, lds + STG_OFF, tid);
        __syncthreads();
        for (int s = 0; s < 16; ++s) {
            if (s + 1 < 16)
                stage512(wsh + (s + 1) * 32, IN_,
                         ((s + 1) & 1) ? lds + H2S_OFF : lds + STG_OFF, tid);
            const char* bb = (s & 1) ? lds + H2S_OFF : lds + STG_OFF;
            const char* ab = lds + XS_OFF + s * 4096;
            do_step(ab, bb, wm, wn, lane, acc);
            __syncthreads();
        }
        epi_relu_lds(lds + H1S_OFF, acc, bs, wm, wn, lq, lr);
        __syncthreads();
    }

    // ---- phase 2: h2 = relu(h1 @ Wm^T + bm), K=256 ----
    {
        f32x4 acc[2][4];
#pragma unroll
        for (int i = 0; i < 2; ++i)
#pragma unroll
            for (int j = 0; j < 4; ++j) acc[i][j] = zero;

        stage512(wmh, HYP_, lds + STG_OFF, tid);
        __syncthreads();
        for (int s = 0; s < 8; ++s) {
            if (s + 1 < 8)
                stage512(wmh + (s + 1) * 32, HYP_,
                         ((s + 1) & 1) ? lds + H2S_OFF : lds + STG_OFF, tid);
            const char* bb = (s & 1) ? lds + H2S_OFF : lds + STG_OFF;
            const char* ab = lds + H1S_OFF + s * 4096;
            do_step(ab, bb, wm, wn, lane, acc);
            __syncthreads();
        }
        epi_relu_lds(lds + H2S_OFF, acc, bm, wm, wn, lq, lr);
        __syncthreads();
    }

    // ---- phases 3+4 per 256-col half: fc & sig arms, 24 pipelined steps ----
#pragma unroll 1
    for (int half = 0; half < 2; ++half) {
        const int c0 = half * 256;
        f32x4 accf[2][4], accs[2][4];
#pragma unroll
        for (int i = 0; i < 2; ++i)
#pragma unroll
            for (int j = 0; j < 4; ++j) { accf[i][j] = zero; accs[i][j] = zero; }

        stage512(weh + (size_t)c0 * HYP_, HYP_, lds + STG_OFF, tid);
        __syncthreads();
        for (int s = 0; s < 24; ++s) {
            const int e = s + 1;
            if (e < 24) {
                char* db = (e & 1) ? lds + H1S_OFF : lds + STG_OFF;
                if (e < 8) stage512(weh + (size_t)c0 * HYP_ + e * 32, HYP_, db, tid);
                else       stage512(w2h + (size_t)c0 * IN_ + (e - 8) * 32, IN_, db, tid);
            }
            const char* bb = (s & 1) ? lds + H1S_OFF : lds + STG_OFF;
            if (s < 8) {
                const char* ab = lds + H2S_OFF + s * 4096;
                do_step(ab, bb, wm, wn, lane, accf);
            } else {
                const char* ab = lds + XS_OFF + (s - 8) * 4096;
                do_step(ab, bb, wm, wn, lane, accs);
            }
            __syncthreads();
        }

        // epilogue: out = (fc + be) * sigmoid(sig + b2), fp32 to HBM
#pragma unroll
        for (int j = 0; j < 4; ++j) {
            const int gcol = c0 + wn * 64 + j * 16 + lr;
            const float bev = be[gcol];
            const float b2v = b2[gcol];
#pragma unroll
            for (int i = 0; i < 2; ++i) {
#pragma unroll
                for (int rg = 0; rg < 4; ++rg) {
                    const int row = m0 + wm * 32 + i * 16 + lq * 4 + rg;
                    const float fc = accf[i][j][rg] + bev;
                    float sg = accs[i][j][rg] + b2v;
                    sg = 1.f / (1.f + __expf(-sg));
                    Out[(size_t)row * HID_ + gcol] = fc * sg;
                }
            }
        }
    }
}

// ---------------------------------------------------------------------------
// Scan: h_t[j] = relu(h_{t-1}[(j-1)&511] + b_t[j]) -> 16384 independent
// diagonal chains (chain r of batch b touches (t, (r+t)&511)). One thread
// per chain, 32-deep register prefetch, in-place over b.
// ---------------------------------------------------------------------------
__global__ __launch_bounds__(64) void srnn_chain(const float* __restrict__ hidden,
                                                 float* bio, float* hlast)
{
    const int g = blockIdx.x * 64 + threadIdx.x;
    const int b = g >> 9;
    const int r = g & 511;
    float* base = bio + (size_t)b * (T_ * HID_);

    float c = hidden[b * HID_ + ((r + 511) & 511)];   // h_{-1}[(r-1) mod 512]

    float buf[32];
#pragma unroll
    for (int u = 0; u < 32; ++u)
        buf[u] = base[u * 512 + ((r + u) & 511)];

    for (int tb = 0; tb < T_; tb += 32) {
#pragma unroll
        for (int u = 0; u < 32; ++u) {
            const int t = tb + u;
            c = fmaxf(c + buf[u], 0.f);
            base[t * 512 + ((r + t) & 511)] = c;
            const int tn = t + 32;
            if (tn < T_)   // uniform branch
                buf[u] = base[tn * 512 + ((r + tn) & 511)];
        }
    }
    hlast[b * HID_ + ((r + 1023) & 511)] = c;
}

extern "C" void kernel_launch(void* const* d_in, const int* in_sizes, int n_in,
                              void* d_out, int out_size, void* d_ws, size_t ws_size,
                              hipStream_t stream)
{
    const float* x      = (const float*)d_in[0];  // [B,T,IN]
    const float* hidden = (const float*)d_in[1];  // [B,HID]
    const float* Ws     = (const float*)d_in[2];  // [HYP,IN]
    const float* bs     = (const float*)d_in[3];
    const float* Wm     = (const float*)d_in[4];  // [HYP,HYP]
    const float* bm     = (const float*)d_in[5];
    const float* We     = (const float*)d_in[6];  // [HID,HYP]
    const float* be     = (const float*)d_in[7];
    const float* W2     = (const float*)d_in[8];  // [HID,IN]
    const float* b2     = (const float*)d_in[9];

    float* outputs = (float*)d_out;                 // [B,T,HID]
    float* hlast   = outputs + (size_t)M_ * HID_;   // [B,HID]

    // workspace: fp16 weights only (~1.3 MB)
    _Float16* wsh = (_Float16*)d_ws;                // [HYP,IN]
    _Float16* wmh = wsh + HYP_ * IN_;               // [HYP,HYP]
    _Float16* weh = wmh + HYP_ * HYP_;              // [HID,HYP]
    _Float16* w2h = weh + HID_ * HYP_;              // [HID,IN]

    cvt_w<<<dim3(288), 256, 0, stream>>>(Ws, wsh, Wm, wmh, We, weh, W2, w2h);
    fused_mlp<<<dim3(M_ / R_), 512, 0, stream>>>(
        x, wsh, bs, wmh, bm, weh, be, w2h, b2, outputs);
    srnn_chain<<<dim3((B_ * HID_) / 64), dim3(64), 0, stream>>>(hidden, outputs, hlast);
}

// Round 7
// 149.611 us; speedup vs baseline: 1.3413x; 1.1908x over previous
//
#include <hip/hip_runtime.h>
#include <math.h>

#define B_   32
#define T_   1024
#define IN_  512
#define HID_ 512
#define HYP_ 256
#define M_   (B_ * T_)   // 32768
#define R_   64          // rows per fused block

// LDS map (bytes): xs 64K | h1s 32K | h2s 32K | stg 16K  = 144 KiB
#define XS_OFF   0
#define H1S_OFF  65536
#define H2S_OFF  98304
#define STG_OFF  131072
#define LDS_BYTES 147456

typedef _Float16 half8_t __attribute__((ext_vector_type(8)));
typedef _Float16 half4_t __attribute__((ext_vector_type(4)));
typedef float    f32x4   __attribute__((ext_vector_type(4)));

typedef __attribute__((address_space(1))) const void* gptr_as1;
typedef __attribute__((address_space(3))) void*       lptr_as3;

__device__ __forceinline__ void gload_lds16(const void* g, void* l) {
    // async global->LDS, 16B/lane; LDS dest = wave-uniform base + lane*16
    __builtin_amdgcn_global_load_lds((gptr_as1)g, (lptr_as3)l, 16, 0, 0);
}

// counted-vmcnt pipeline primitives (T3/T4): loads for tile t+1 stay in
// flight across both barriers; only tile t's loads are waited on.
#define VMCNT2() asm volatile("s_waitcnt vmcnt(2)" ::: "memory")
#define VMCNT0() asm volatile("s_waitcnt vmcnt(0)" ::: "memory")
#define SBAR()   __builtin_amdgcn_s_barrier()
#define SCHED0() __builtin_amdgcn_sched_barrier(0)

// ---------------------------------------------------------------------------
// fp32 -> fp16 weights only (1.3 MB out). 2048 elems/block.
// ---------------------------------------------------------------------------
__global__ __launch_bounds__(256) void cvt_w(
    const float* __restrict__ Ws, _Float16* __restrict__ wsh,
    const float* __restrict__ Wm, _Float16* __restrict__ wmh,
    const float* __restrict__ We, _Float16* __restrict__ weh,
    const float* __restrict__ W2, _Float16* __restrict__ w2h)
{
    const int blk = blockIdx.x;
    const float* src; _Float16* dst; int base;
    if      (blk < 64)  { src = Ws; dst = wsh; base = blk; }
    else if (blk < 96)  { src = Wm; dst = wmh; base = blk - 64; }
    else if (blk < 160) { src = We; dst = weh; base = blk - 96; }
    else                { src = W2; dst = w2h; base = blk - 160; }
    const int i = base * 2048 + threadIdx.x * 8;
    f32x4 v0 = *(const f32x4*)(src + i);
    f32x4 v1 = *(const f32x4*)(src + i + 4);
    half8_t h;
    h[0] = (_Float16)v0[0]; h[1] = (_Float16)v0[1];
    h[2] = (_Float16)v0[2]; h[3] = (_Float16)v0[3];
    h[4] = (_Float16)v1[0]; h[5] = (_Float16)v1[1];
    h[6] = (_Float16)v1[2]; h[7] = (_Float16)v1[3];
    *(half8_t*)(dst + i) = h;
}

// ---------------------------------------------------------------------------
// Fragment-order + XOR-swizzled staging of a 256-row x 32-half weight tile.
// LDS slot s (16B): g = s>>6, c2 = (s>>4)&3, rho = s&15 holds source row
// g*16 + (rho ^ c2), k-bytes [c2*16, c2*16+16). The XOR spreads the k-chunk
// dimension across banks; the read side compensates with the same XOR in the
// lane offset (lsw). Source address carries the permutation; LDS dest stays
// linear (global_load_lds rule: both-sides-or-neither).
// ---------------------------------------------------------------------------
__device__ __forceinline__ void stage512(const _Float16* src, int K,
                                         char* ldsbase, int tid)
{
#pragma unroll
    for (int q = 0; q < 2; ++q) {
        const int s = q * 512 + tid;
        const int g = s >> 6, c2 = (s >> 4) & 3, r = (s & 15) ^ c2;
        const char* gp = (const char*)src + (size_t)(g * 16 + r) * (K * 2) + c2 * 16;
        char* lp = ldsbase + (q * 512 + (tid & ~63)) * 16;   // wave-uniform
        gload_lds16(gp, lp);
    }
}

// one k-step: A frag-group pair (wm) x B frag-quad (wn), 8 MFMAs.
// lsw = (lane ^ ((lane>>4)&3)) * 16  -- XOR-compensated lane byte offset.
__device__ __forceinline__ void do_step(const char* ab, const char* bb,
                                        int wm, int wn, int lsw,
                                        f32x4 acc[2][4])
{
    half8_t af0 = *(const half8_t*)(ab + (wm * 2 + 0) * 1024 + lsw);
    half8_t af1 = *(const half8_t*)(ab + (wm * 2 + 1) * 1024 + lsw);
#pragma unroll
    for (int j = 0; j < 4; ++j) {
        half8_t wf = *(const half8_t*)(bb + (wn * 4 + j) * 1024 + lsw);
        acc[0][j] = __builtin_amdgcn_mfma_f32_16x16x32_f16(af0, wf, acc[0][j], 0, 0, 0);
        acc[1][j] = __builtin_amdgcn_mfma_f32_16x16x32_f16(af1, wf, acc[1][j], 0, 0, 0);
    }
}

// bias+relu epilogue, scatter fp16 into XOR-swizzled fragment-order LDS
__device__ __forceinline__ void epi_relu_lds(char* dst, const f32x4 acc[2][4],
                                             const float* __restrict__ bias,
                                             int wm, int wn, int lq, int lr)
{
#pragma unroll
    for (int j = 0; j < 4; ++j) {
        const int col = wn * 64 + j * 16 + lr;
        const float bv = bias[col];
        const int cc2 = (col & 31) >> 3;
        const int cpart = (col >> 5) * 4096 + cc2 * 256 + (col & 7) * 2;
#pragma unroll
        for (int i = 0; i < 2; ++i) {
#pragma unroll
            for (int rg = 0; rg < 4; ++rg) {
                const int row = wm * 32 + i * 16 + lq * 4 + rg;
                const float v = fmaxf(acc[i][j][rg] + bv, 0.f);
                *(_Float16*)(dst + cpart + (row >> 4) * 1024 +
                             (((row & 15) ^ cc2)) * 16) = (_Float16)v;
            }
        }
    }
}

// ---------------------------------------------------------------------------
// Fused MLP with counted-vmcnt 2-deep pipeline. Per 64-row m-tile, x lives in
// LDS (converted once); h1,h2 live in LDS; per k-step only a 16 KiB weight
// tile is staged, double-buffered into dead LDS regions:
//   P1: h1 = relu(x@Ws^T+bs)   K=512, 16 steps, dbuf STG/H2S(dead)
//   P2: h2 = relu(h1@Wm^T+bm)  K=256,  8 steps, dbuf STG/H2S(dead-after-read)
//   P3: out = (h2@We^T+be)*sigmoid(x@W2^T+b2), per 256-col half 8+16 steps,
//       dbuf STG/H1S(dead)
// Steady step: stage(t+1); vmcnt(2); bar; MFMA(t); bar  -- t+1's loads are
// never drained (T4). setprio wraps the MFMA cluster (T5).
// ---------------------------------------------------------------------------
__global__ __launch_bounds__(512, 2) void fused_mlp(
    const float* __restrict__ x,
    const _Float16* __restrict__ wsh, const float* __restrict__ bs,
    const _Float16* __restrict__ wmh, const float* __restrict__ bm,
    const _Float16* __restrict__ weh, const float* __restrict__ be,
    const _Float16* __restrict__ w2h, const float* __restrict__ b2,
    float* __restrict__ Out)
{
    __shared__ __align__(16) char lds[LDS_BYTES];

    const int tid  = threadIdx.x;
    const int m0   = blockIdx.x * R_;
    const int lane = tid & 63;
    const int wave = tid >> 6;
    const int wm = wave >> 2;        // 0..1  (m)
    const int wn = wave & 3;         // 0..3  (n)
    const int lq = lane >> 4, lr = lane & 15;
    const int lsw = (lane ^ ((lane >> 4) & 3)) * 16;   // XOR-compensated

    // issue first weight tile early (async), then convert x while it flies
    stage512(wsh, IN_, lds + STG_OFF, tid);

    // ---- x tile: fp32 HBM -> fp16 XOR-swizzled fragment-order LDS ----
#pragma unroll
    for (int v = 0; v < 16; ++v) {
        const int idx = v * 2048 + tid * 4;      // 0..32767
        const int row = idx >> 9, k = idx & 511; // k % 4 == 0
        f32x4 xv = *(const f32x4*)(x + (size_t)(m0 + row) * IN_ + k);
        half4_t h;
        h[0] = (_Float16)xv[0]; h[1] = (_Float16)xv[1];
        h[2] = (_Float16)xv[2]; h[3] = (_Float16)xv[3];
        const int c2 = (k & 31) >> 3;
        const int byteoff = XS_OFF + (k >> 5) * 4096 + (row >> 4) * 1024 +
                            c2 * 256 + (((row & 15) ^ c2)) * 16 + (k & 7) * 2;
        *(half4_t*)(lds + byteoff) = h;
    }
    __syncthreads();   // x in LDS; (vmcnt drain here also covers tile 0 -- ok once)

    const f32x4 zero = {0.f, 0.f, 0.f, 0.f};

    // ---- phase 1: h1 = relu(x @ Ws^T + bs), K=512, 16 steps ----
    {
        f32x4 acc[2][4];
#pragma unroll
        for (int i = 0; i < 2; ++i)
#pragma unroll
            for (int j = 0; j < 4; ++j) acc[i][j] = zero;

#pragma unroll 2
        for (int s = 0; s < 15; ++s) {
            stage512(wsh + (s + 1) * 32, IN_,
                     ((s + 1) & 1) ? lds + H2S_OFF : lds + STG_OFF, tid);
            VMCNT2(); SCHED0();
            SBAR(); SCHED0();
            const char* bb = (s & 1) ? lds + H2S_OFF : lds + STG_OFF;
            __builtin_amdgcn_s_setprio(1);
            do_step(lds + XS_OFF + s * 4096, bb, wm, wn, lsw, acc);
            __builtin_amdgcn_s_setprio(0);
            SCHED0();
            SBAR(); SCHED0();
        }
        VMCNT0(); SCHED0(); SBAR(); SCHED0();
        do_step(lds + XS_OFF + 15 * 4096, lds + H2S_OFF, wm, wn, lsw, acc);
        __syncthreads();
        epi_relu_lds(lds + H1S_OFF, acc, bs, wm, wn, lq, lr);
        __syncthreads();
    }

    // ---- phase 2: h2 = relu(h1 @ Wm^T + bm), K=256, 8 steps ----
    {
        f32x4 acc[2][4];
#pragma unroll
        for (int i = 0; i < 2; ++i)
#pragma unroll
            for (int j = 0; j < 4; ++j) acc[i][j] = zero;

        stage512(wmh, HYP_, lds + STG_OFF, tid);
#pragma unroll 2
        for (int s = 0; s < 7; ++s) {
            stage512(wmh + (s + 1) * 32, HYP_,
                     ((s + 1) & 1) ? lds + H2S_OFF : lds + STG_OFF, tid);
            VMCNT2(); SCHED0();
            SBAR(); SCHED0();
            const char* bb = (s & 1) ? lds + H2S_OFF : lds + STG_OFF;
            __builtin_amdgcn_s_setprio(1);
            do_step(lds + H1S_OFF + s * 4096, bb, wm, wn, lsw, acc);
            __builtin_amdgcn_s_setprio(0);
            SCHED0();
            SBAR(); SCHED0();
        }
        VMCNT0(); SCHED0(); SBAR(); SCHED0();
        do_step(lds + H1S_OFF + 7 * 4096, lds + H2S_OFF, wm, wn, lsw, acc);
        __syncthreads();
        epi_relu_lds(lds + H2S_OFF, acc, bm, wm, wn, lq, lr);
        __syncthreads();
    }

    // ---- phases 3+4 per 256-col half: fc & sig arms, 24 pipelined steps ----
#pragma unroll 1
    for (int half = 0; half < 2; ++half) {
        const int c0 = half * 256;
        f32x4 accf[2][4], accs[2][4];
#pragma unroll
        for (int i = 0; i < 2; ++i)
#pragma unroll
            for (int j = 0; j < 4; ++j) { accf[i][j] = zero; accs[i][j] = zero; }

        stage512(weh + (size_t)c0 * HYP_, HYP_, lds + STG_OFF, tid);
#pragma unroll 2
        for (int s = 0; s < 23; ++s) {
            const int e = s + 1;
            char* db = (e & 1) ? lds + H1S_OFF : lds + STG_OFF;
            if (e < 8) stage512(weh + (size_t)c0 * HYP_ + e * 32, HYP_, db, tid);
            else       stage512(w2h + (size_t)c0 * IN_ + (e - 8) * 32, IN_, db, tid);
            VMCNT2(); SCHED0();
            SBAR(); SCHED0();
            const char* bb = (s & 1) ? lds + H1S_OFF : lds + STG_OFF;
            __builtin_amdgcn_s_setprio(1);
            if (s < 8) do_step(lds + H2S_OFF + s * 4096, bb, wm, wn, lsw, accf);
            else       do_step(lds + XS_OFF + (s - 8) * 4096, bb, wm, wn, lsw, accs);
            __builtin_amdgcn_s_setprio(0);
            SCHED0();
            SBAR(); SCHED0();
        }
        VMCNT0(); SCHED0(); SBAR(); SCHED0();
        do_step(lds + XS_OFF + 15 * 4096, lds + H1S_OFF, wm, wn, lsw, accs);
        __syncthreads();   // all reads of H1S/STG done before next half restages

        // epilogue: out = (fc + be) * sigmoid(sig + b2), fp32 to HBM
#pragma unroll
        for (int j = 0; j < 4; ++j) {
            const int gcol = c0 + wn * 64 + j * 16 + lr;
            const float bev = be[gcol];
            const float b2v = b2[gcol];
#pragma unroll
            for (int i = 0; i < 2; ++i) {
#pragma unroll
                for (int rg = 0; rg < 4; ++rg) {
                    const int row = m0 + wm * 32 + i * 16 + lq * 4 + rg;
                    const float fc = accf[i][j][rg] + bev;
                    float sg = accs[i][j][rg] + b2v;
                    sg = 1.f / (1.f + __expf(-sg));
                    Out[(size_t)row * HID_ + gcol] = fc * sg;
                }
            }
        }
        __syncthreads();   // drain stores + protect H1S before half=1 staging
    }
}

// ---------------------------------------------------------------------------
// Scan: h_t[j] = relu(h_{t-1}[(j-1)&511] + b_t[j]) -> 16384 independent
// diagonal chains (chain r of batch b touches (t, (r+t)&511)). One thread
// per chain, 64-deep register prefetch (16 KiB/wave in flight -> ~4 MB
// device-wide, covers HBM latency at full BW), in-place over b.
// ---------------------------------------------------------------------------
__global__ __launch_bounds__(64) void srnn_chain(const float* __restrict__ hidden,
                                                 float* bio, float* hlast)
{
    const int g = blockIdx.x * 64 + threadIdx.x;
    const int b = g >> 9;
    const int r = g & 511;
    float* base = bio + (size_t)b * (T_ * HID_);

    float c = hidden[b * HID_ + ((r + 511) & 511)];   // h_{-1}[(r-1) mod 512]

    float buf[64];
#pragma unroll
    for (int u = 0; u < 64; ++u)
        buf[u] = base[u * 512 + ((r + u) & 511)];

    for (int tb = 0; tb < T_; tb += 64) {
#pragma unroll
        for (int u = 0; u < 64; ++u) {
            const int t = tb + u;
            c = fmaxf(c + buf[u], 0.f);
            base[t * 512 + ((r + t) & 511)] = c;
            const int tn = t + 64;
            if (tn < T_)   // uniform branch
                buf[u] = base[tn * 512 + ((r + tn) & 511)];
        }
    }
    hlast[b * HID_ + ((r + 1023) & 511)] = c;
}

extern "C" void kernel_launch(void* const* d_in, const int* in_sizes, int n_in,
                              void* d_out, int out_size, void* d_ws, size_t ws_size,
                              hipStream_t stream)
{
    const float* x      = (const float*)d_in[0];  // [B,T,IN]
    const float* hidden = (const float*)d_in[1];  // [B,HID]
    const float* Ws     = (const float*)d_in[2];  // [HYP,IN]
    const float* bs     = (const float*)d_in[3];
    const float* Wm     = (const float*)d_in[4];  // [HYP,HYP]
    const float* bm     = (const float*)d_in[5];
    const float* We     = (const float*)d_in[6];  // [HID,HYP]
    const float* be     = (const float*)d_in[7];
    const float* W2     = (const float*)d_in[8];  // [HID,IN]
    const float* b2     = (const float*)d_in[9];

    float* outputs = (float*)d_out;                 // [B,T,HID]
    float* hlast   = outputs + (size_t)M_ * HID_;   // [B,HID]

    // workspace: fp16 weights only (~1.3 MB)
    _Float16* wsh = (_Float16*)d_ws;                // [HYP,IN]
    _Float16* wmh = wsh + HYP_ * IN_;               // [HYP,HYP]
    _Float16* weh = wmh + HYP_ * HYP_;              // [HID,HYP]
    _Float16* w2h = weh + HID_ * HYP_;              // [HID,IN]

    cvt_w<<<dim3(288), 256, 0, stream>>>(Ws, wsh, Wm, wmh, We, weh, W2, w2h);
    fused_mlp<<<dim3(M_ / R_), 512, 0, stream>>>(
        x, wsh, bs, wmh, bm, weh, be, w2h, b2, outputs);
    srnn_chain<<<dim3((B_ * HID_) / 64), dim3(64), 0, stream>>>(hidden, outputs, hlast);
}

// Round 8
// 133.421 us; speedup vs baseline: 1.5041x; 1.1213x over previous
//
#include <hip/hip_runtime.h>
#include <math.h>

#define B_   32
#define T_   1024
#define IN_  512
#define HID_ 512
#define HYP_ 256
#define M_   (B_ * T_)   // 32768
#define R_   128         // rows per fused block -> 256 blocks = 1/CU, one round

// LDS map (bytes): h1s 64K | h2s 64K | stg 16K = 144 KiB
// Stage dbufs live in phase-dead regions:
//  P1: A(xh)-> H2S+0/+8K, W-odd -> H1S+0 (epi overwrites H1S after)
//  P2: W-odd -> H2S+0 (A-chunks dead; epi overwrites H2S after)
//  P3/4: xh -> H1S+0/+8K, W-odd -> H1S+16K (H1S dead after P2)
#define H1S  0
#define H2S  65536
#define STG  131072
#define LDS_BYTES 147456

typedef _Float16 half8_t __attribute__((ext_vector_type(8)));
typedef float    f32x4   __attribute__((ext_vector_type(4)));

typedef __attribute__((address_space(1))) const void* gptr_as1;
typedef __attribute__((address_space(3))) void*       lptr_as3;

__device__ __forceinline__ void gload_lds16(const void* g, void* l) {
    __builtin_amdgcn_global_load_lds((gptr_as1)g, (lptr_as3)l, 16, 0, 0);
}

// counted-vmcnt pipeline (T4): literal = loads just issued for tile t+1;
// waits tile t complete while t+1 stays in flight.
#define VMCNT3() asm volatile("s_waitcnt vmcnt(3)" ::: "memory")
#define VMCNT2() asm volatile("s_waitcnt vmcnt(2)" ::: "memory")
#define VMCNT0() asm volatile("s_waitcnt vmcnt(0)" ::: "memory")
#define SBAR()   __builtin_amdgcn_s_barrier()
#define SCHED0() __builtin_amdgcn_sched_barrier(0)

// ---------------------------------------------------------------------------
// fp32 -> fp16: x (8192 blocks) + Ws(64) + Wm(32) + We(64) + W2(128).
// ---------------------------------------------------------------------------
__global__ __launch_bounds__(256) void cvt_all(
    const float* __restrict__ x,  _Float16* __restrict__ xh,
    const float* __restrict__ Ws, _Float16* __restrict__ wsh,
    const float* __restrict__ Wm, _Float16* __restrict__ wmh,
    const float* __restrict__ We, _Float16* __restrict__ weh,
    const float* __restrict__ W2, _Float16* __restrict__ w2h)
{
    const int blk = blockIdx.x;
    const float* src; _Float16* dst; int base;
    if      (blk < 8192) { src = x;  dst = xh;  base = blk; }
    else if (blk < 8256) { src = Ws; dst = wsh; base = blk - 8192; }
    else if (blk < 8288) { src = Wm; dst = wmh; base = blk - 8256; }
    else if (blk < 8352) { src = We; dst = weh; base = blk - 8288; }
    else                 { src = W2; dst = w2h; base = blk - 8352; }
    const int i = base * 2048 + threadIdx.x * 8;
    f32x4 v0 = *(const f32x4*)(src + i);
    f32x4 v1 = *(const f32x4*)(src + i + 4);
    half8_t h;
    h[0] = (_Float16)v0[0]; h[1] = (_Float16)v0[1];
    h[2] = (_Float16)v0[2]; h[3] = (_Float16)v0[3];
    h[4] = (_Float16)v1[0]; h[5] = (_Float16)v1[1];
    h[6] = (_Float16)v1[2]; h[7] = (_Float16)v1[3];
    *(half8_t*)(dst + i) = h;
}

// ---------------------------------------------------------------------------
// Fragment-order + XOR-swizzled staging. Slot s (16B): g=s>>6, c2=(s>>4)&3,
// rho=s&15 holds source row g*16+(rho^c2), k-bytes [c2*16,c2*16+16). Read side
// compensates via lsw. Source carries the permutation; LDS dest linear.
// stage512: 256-row x 32-half W tile (16 KiB), 2 loads/thread (512 thr).
// stageA:   128-row x 32-half A chunk (8 KiB), 1 load/thread.
// ---------------------------------------------------------------------------
__device__ __forceinline__ void stage512(const _Float16* src, int K,
                                         char* ldsbase, int tid)
{
#pragma unroll
    for (int q = 0; q < 2; ++q) {
        const int s = q * 512 + tid;
        const int g = s >> 6, c2 = (s >> 4) & 3, r = (s & 15) ^ c2;
        const char* gp = (const char*)src + (size_t)(g * 16 + r) * (K * 2) + c2 * 16;
        char* lp = ldsbase + (q * 512 + (tid & ~63)) * 16;
        gload_lds16(gp, lp);
    }
}

__device__ __forceinline__ void stageA(const _Float16* src, int K,
                                       char* ldsbase, int tid)
{
    const int s = tid;                       // 0..511 -> 8 frags
    const int g = s >> 6, c2 = (s >> 4) & 3, r = (s & 15) ^ c2;
    const char* gp = (const char*)src + (size_t)(g * 16 + r) * (K * 2) + c2 * 16;
    char* lp = ldsbase + (tid & ~63) * 16;
    gload_lds16(gp, lp);
}

// one k-step: 4 A-frags (wm) x 4 B-frags (wn) = 16 MFMAs
__device__ __forceinline__ void do_step16(const char* ab, const char* bb,
                                          int wm, int wn, int lsw,
                                          f32x4 acc[4][4])
{
    half8_t af[4], wf[4];
#pragma unroll
    for (int i = 0; i < 4; ++i)
        af[i] = *(const half8_t*)(ab + (wm * 4 + i) * 1024 + lsw);
#pragma unroll
    for (int j = 0; j < 4; ++j)
        wf[j] = *(const half8_t*)(bb + (wn * 4 + j) * 1024 + lsw);
#pragma unroll
    for (int i = 0; i < 4; ++i)
#pragma unroll
        for (int j = 0; j < 4; ++j)
            acc[i][j] = __builtin_amdgcn_mfma_f32_16x16x32_f16(af[i], wf[j], acc[i][j], 0, 0, 0);
}

// bias+relu epilogue: scatter fp16 into XOR-swizzled fragment-order LDS
// (A-layout for the next phase; k-chunk stride 8192 B for R_=128).
__device__ __forceinline__ void epi_relu_lds(char* dst, const f32x4 acc[4][4],
                                             const float* __restrict__ bias,
                                             int wm, int wn, int lq, int lr)
{
#pragma unroll
    for (int j = 0; j < 4; ++j) {
        const int col = wn * 64 + j * 16 + lr;
        const float bv = bias[col];
        const int cc2 = (col & 31) >> 3;
        const int cpart = (col >> 5) * 8192 + cc2 * 256 + (col & 7) * 2;
#pragma unroll
        for (int i = 0; i < 4; ++i) {
#pragma unroll
            for (int rg = 0; rg < 4; ++rg) {
                const int row = wm * 64 + i * 16 + lq * 4 + rg;
                const float v = fmaxf(acc[i][j][rg] + bv, 0.f);
                *(_Float16*)(dst + cpart + (row >> 4) * 1024 +
                             (((row & 15) ^ cc2)) * 16) = (_Float16)v;
            }
        }
    }
}

// ---------------------------------------------------------------------------
// Fused MLP v2: 256 blocks x 512 threads, R=128 rows/block (one grid round).
//   P1: h1 = relu(xh@Ws^T+bs)   K=512, 16 steps (stage xh 8K + Ws 16K)
//   P2: h2 = relu(h1@Wm^T+bm)   K=256,  8 steps (stage Wm 16K; A=H1S)
//   P3/4 per 256-col half: fc (8 steps, A=H2S) then sig (16 steps, A=xh
//        streamed again) -> out = (fc+be)*sigmoid(sig+b2)
// Steady step: stage(t+1); vmcnt(L_{t+1}); bar; 16 MFMA (setprio); bar.
// ---------------------------------------------------------------------------
__global__ __launch_bounds__(512, 2) void fused_mlp(
    const _Float16* __restrict__ xh,
    const _Float16* __restrict__ wsh, const float* __restrict__ bs,
    const _Float16* __restrict__ wmh, const float* __restrict__ bm,
    const _Float16* __restrict__ weh, const float* __restrict__ be,
    const _Float16* __restrict__ w2h, const float* __restrict__ b2,
    float* __restrict__ Out)
{
    __shared__ __align__(16) char lds[LDS_BYTES];

    const int tid  = threadIdx.x;
    const int m0   = blockIdx.x * R_;
    const int lane = tid & 63;
    const int wave = tid >> 6;
    const int wm = wave >> 2;        // 0..1 (m, 64 rows each)
    const int wn = wave & 3;         // 0..3 (n, 64 cols each)
    const int lq = lane >> 4, lr = lane & 15;
    const int lsw = (lane ^ ((lane >> 4) & 3)) * 16;

    const _Float16* xrow = xh + (size_t)m0 * IN_;
    const f32x4 zero = {0.f, 0.f, 0.f, 0.f};

    // ---- P1: h1 = relu(xh @ Ws^T + bs), K=512, 16 steps ----
    {
        f32x4 acc[4][4];
#pragma unroll
        for (int i = 0; i < 4; ++i)
#pragma unroll
            for (int j = 0; j < 4; ++j) acc[i][j] = zero;

        stageA(xrow, IN_, lds + H2S, tid);
        stage512(wsh, IN_, lds + STG, tid);
        for (int s = 0; s < 15; ++s) {
            const int e = s + 1;
            stageA(xrow + e * 32, IN_, lds + H2S + (e & 1) * 8192, tid);
            stage512(wsh + e * 32, IN_, (e & 1) ? lds + H1S : lds + STG, tid);
            VMCNT3(); SCHED0(); SBAR(); SCHED0();
            const char* ab = lds + H2S + (s & 1) * 8192;
            const char* bb = (s & 1) ? lds + H1S : lds + STG;
            __builtin_amdgcn_s_setprio(1);
            do_step16(ab, bb, wm, wn, lsw, acc);
            __builtin_amdgcn_s_setprio(0);
            SCHED0(); SBAR(); SCHED0();
        }
        VMCNT0(); SCHED0(); SBAR(); SCHED0();
        do_step16(lds + H2S + 8192, lds + H1S, wm, wn, lsw, acc);  // s=15 (odd)
        __syncthreads();
        epi_relu_lds(lds + H1S, acc, bs, wm, wn, lq, lr);
        __syncthreads();
    }

    // ---- P2: h2 = relu(h1 @ Wm^T + bm), K=256, 8 steps ----
    {
        f32x4 acc[4][4];
#pragma unroll
        for (int i = 0; i < 4; ++i)
#pragma unroll
            for (int j = 0; j < 4; ++j) acc[i][j] = zero;

        stage512(wmh, HYP_, lds + STG, tid);
        for (int s = 0; s < 7; ++s) {
            const int e = s + 1;
            stage512(wmh + e * 32, HYP_, (e & 1) ? lds + H2S : lds + STG, tid);
            VMCNT2(); SCHED0(); SBAR(); SCHED0();
            const char* ab = lds + H1S + s * 8192;
            const char* bb = (s & 1) ? lds + H2S : lds + STG;
            __builtin_amdgcn_s_setprio(1);
            do_step16(ab, bb, wm, wn, lsw, acc);
            __builtin_amdgcn_s_setprio(0);
            SCHED0(); SBAR(); SCHED0();
        }
        VMCNT0(); SCHED0(); SBAR(); SCHED0();
        do_step16(lds + H1S + 7 * 8192, lds + H2S, wm, wn, lsw, acc); // s=7 (odd)
        __syncthreads();
        epi_relu_lds(lds + H2S, acc, bm, wm, wn, lq, lr);
        __syncthreads();
    }

    // ---- P3/P4 per 256-col half: fc (8) + sig (16) pipelined steps ----
#pragma unroll 1
    for (int half = 0; half < 2; ++half) {
        const int c0 = half * 256;
        const _Float16* wehh = weh + (size_t)c0 * HYP_;
        const _Float16* w2hh = w2h + (size_t)c0 * IN_;
        f32x4 accf[4][4], accs[4][4];
#pragma unroll
        for (int i = 0; i < 4; ++i)
#pragma unroll
            for (int j = 0; j < 4; ++j) { accf[i][j] = zero; accs[i][j] = zero; }

        stage512(wehh, HYP_, lds + STG, tid);          // fc tile 0 (even)
        for (int s = 0; s < 7; ++s) {                  // stage fc tiles 1..7
            const int e = s + 1;
            stage512(wehh + e * 32, HYP_, (e & 1) ? lds + H1S + 16384 : lds + STG, tid);
            VMCNT2(); SCHED0(); SBAR(); SCHED0();
            const char* ab = lds + H2S + s * 8192;
            const char* bb = (s & 1) ? lds + H1S + 16384 : lds + STG;
            __builtin_amdgcn_s_setprio(1);
            do_step16(ab, bb, wm, wn, lsw, accf);
            __builtin_amdgcn_s_setprio(0);
            SCHED0(); SBAR(); SCHED0();
        }
        {   // s=7: stage sig tile e=8 (ts=0, even parity), compute fc tile 7
            stageA(xrow, IN_, lds + H1S, tid);
            stage512(w2hh, IN_, lds + STG, tid);
            VMCNT3(); SCHED0(); SBAR(); SCHED0();
            __builtin_amdgcn_s_setprio(1);
            do_step16(lds + H2S + 7 * 8192, lds + H1S + 16384, wm, wn, lsw, accf);
            __builtin_amdgcn_s_setprio(0);
            SCHED0(); SBAR(); SCHED0();
        }
        for (int s = 8; s < 23; ++s) {                 // stage sig tiles 1..15
            const int e = s + 1, ts = e - 8;
            stageA(xrow + ts * 32, IN_, lds + H1S + (e & 1) * 8192, tid);
            stage512(w2hh + ts * 32, IN_, (e & 1) ? lds + H1S + 16384 : lds + STG, tid);
            VMCNT3(); SCHED0(); SBAR(); SCHED0();
            const char* ab = lds + H1S + (s & 1) * 8192;
            const char* bb = (s & 1) ? lds + H1S + 16384 : lds + STG;
            __builtin_amdgcn_s_setprio(1);
            do_step16(ab, bb, wm, wn, lsw, accs);
            __builtin_amdgcn_s_setprio(0);
            SCHED0(); SBAR(); SCHED0();
        }
        VMCNT0(); SCHED0(); SBAR(); SCHED0();
        do_step16(lds + H1S + 8192, lds + H1S + 16384, wm, wn, lsw, accs); // s=23 (odd)
        __syncthreads();

        // epilogue: out = (fc + be) * sigmoid(sig + b2)
#pragma unroll
        for (int j = 0; j < 4; ++j) {
            const int gcol = c0 + wn * 64 + j * 16 + lr;
            const float bev = be[gcol];
            const float b2v = b2[gcol];
#pragma unroll
            for (int i = 0; i < 4; ++i) {
#pragma unroll
                for (int rg = 0; rg < 4; ++rg) {
                    const int row = m0 + wm * 64 + i * 16 + lq * 4 + rg;
                    const float fc = accf[i][j][rg] + bev;
                    float sg = accs[i][j][rg] + b2v;
                    sg = 1.f / (1.f + __expf(-sg));
                    Out[(size_t)row * HID_ + gcol] = fc * sg;
                }
            }
        }
        __syncthreads();   // protect H1S/STG before half=1 restages
    }
}

// ---------------------------------------------------------------------------
// Scan: 16384 independent diagonal chains (chain r of batch b touches
// (t, (r+t)&511)). One thread/chain, 64-deep register prefetch, in-place.
// ---------------------------------------------------------------------------
__global__ __launch_bounds__(64) void srnn_chain(const float* __restrict__ hidden,
                                                 float* bio, float* hlast)
{
    const int g = blockIdx.x * 64 + threadIdx.x;
    const int b = g >> 9;
    const int r = g & 511;
    float* base = bio + (size_t)b * (T_ * HID_);

    float c = hidden[b * HID_ + ((r + 511) & 511)];

    float buf[64];
#pragma unroll
    for (int u = 0; u < 64; ++u)
        buf[u] = base[u * 512 + ((r + u) & 511)];

    for (int tb = 0; tb < T_; tb += 64) {
#pragma unroll
        for (int u = 0; u < 64; ++u) {
            const int t = tb + u;
            c = fmaxf(c + buf[u], 0.f);
            base[t * 512 + ((r + t) & 511)] = c;
            const int tn = t + 64;
            if (tn < T_)
                buf[u] = base[tn * 512 + ((r + tn) & 511)];
        }
    }
    hlast[b * HID_ + ((r + 1023) & 511)] = c;
}

extern "C" void kernel_launch(void* const* d_in, const int* in_sizes, int n_in,
                              void* d_out, int out_size, void* d_ws, size_t ws_size,
                              hipStream_t stream)
{
    const float* x      = (const float*)d_in[0];  // [B,T,IN]
    const float* hidden = (const float*)d_in[1];  // [B,HID]
    const float* Ws     = (const float*)d_in[2];  // [HYP,IN]
    const float* bs     = (const float*)d_in[3];
    const float* Wm     = (const float*)d_in[4];  // [HYP,HYP]
    const float* bm     = (const float*)d_in[5];
    const float* We     = (const float*)d_in[6];  // [HID,HYP]
    const float* be     = (const float*)d_in[7];
    const float* W2     = (const float*)d_in[8];  // [HID,IN]
    const float* b2     = (const float*)d_in[9];

    float* outputs = (float*)d_out;                 // [B,T,HID]
    float* hlast   = outputs + (size_t)M_ * HID_;   // [B,HID]

    // workspace: xh 32MB | fp16 weights ~1.3MB
    _Float16* xh  = (_Float16*)d_ws;                // [M,IN]
    _Float16* wsh = xh + (size_t)M_ * IN_;          // [HYP,IN]
    _Float16* wmh = wsh + HYP_ * IN_;               // [HYP,HYP]
    _Float16* weh = wmh + HYP_ * HYP_;              // [HID,HYP]
    _Float16* w2h = weh + HID_ * HYP_;              // [HID,IN]

    cvt_all<<<dim3(8480), 256, 0, stream>>>(x, xh, Ws, wsh, Wm, wmh, We, weh, W2, w2h);
    fused_mlp<<<dim3(M_ / R_), 512, 0, stream>>>(
        xh, wsh, bs, wmh, bm, weh, be, w2h, b2, outputs);
    srnn_chain<<<dim3((B_ * HID_) / 64), dim3(64), 0, stream>>>(hidden, outputs, hlast);
}